// Round 10
// baseline (361.613 us; speedup 1.0000x reference)
//
#include <hip/hip_runtime.h>
#include <stdint.h>

#define BB 4
#define SS 2048
#define DD 512
#define NTP 16            // S/128 q-units per batch
#define NEG_BIG -1e30f
#define RESC_THR 4.0f     // defer-max threshold
#define MAXR 8            // max chunks per q-unit (CC>=20 -> rt<=7)

typedef __attribute__((ext_vector_type(4))) float f32x4;
typedef __attribute__((ext_vector_type(8))) _Float16 f16x8;
typedef __attribute__((ext_vector_type(4))) _Float16 f16x4;

typedef __attribute__((address_space(1))) void GV;
typedef __attribute__((address_space(3))) void LV;

union PK4 { _Float16 h[4]; uint2 u; };

// chunks per q-unit tp (128 q rows) for chunk size CC (in 16-kv tiles)
__device__ __host__ __forceinline__ int rt2(int tp, int CC) {
  return (8 * (tp + 1) + CC - 1) / CC;
}

// ---------------------------------------------------------------------------
// Prep: K -> fp16 tile images in exact LDS byte layout (XOR swizzle baked in),
//       V -> pair-transposed fp16 images. One (b, 16-kv-tile) per block.
// (byte-identical to round 6 — verified)
// ---------------------------------------------------------------------------
__global__ __launch_bounds__(256)
void prep_kernel(const float* __restrict__ K, const float* __restrict__ V,
                 char* __restrict__ PREP)
{
  const int blk = blockIdx.x;
  const int b   = blk >> 7;
  const int j   = blk & 127;
  const int tid = threadIdx.x;
  char* img = PREP + (size_t)blk * 32768;

  #pragma unroll
  for (int i = 0; i < 8; ++i) {
    int chunk = tid + 256 * i;
    int rr = chunk >> 7;
    int cc = (chunk & 127) << 2;
    float4 a = *(const float4*)(K + ((size_t)(b * SS + j * 16 + rr)) * DD + cc);
    PK4 p; p.h[0] = (_Float16)a.x; p.h[1] = (_Float16)a.y;
           p.h[2] = (_Float16)a.z; p.h[3] = (_Float16)a.w;
    int off = rr * 1024 + ((cc * 2) ^ ((rr & 7) << 4));
    *(uint2*)(img + off) = p.u;
  }

  #pragma unroll
  for (int half = 0; half < 2; ++half) {
    int d = tid + 256 * half;
    const float* vp = V + ((size_t)(b * SS + j * 16)) * DD + d;
    int e = d >> 5, mm = d & 15, p = (d >> 4) & 1;
    #pragma unroll
    for (int kq4 = 0; kq4 < 4; ++kq4) {
      PK4 pk;
      pk.h[0] = (_Float16)vp[(kq4 * 4 + 0) * DD];
      pk.h[1] = (_Float16)vp[(kq4 * 4 + 1) * DD];
      pk.h[2] = (_Float16)vp[(kq4 * 4 + 2) * DD];
      pk.h[3] = (_Float16)vp[(kq4 * 4 + 3) * DD];
      int slot = (kq4 ^ (mm & 3)) & 3;
      *(uint2*)(img + 16384 + e * 1024 + mm * 64 + slot * 16 + p * 8) = pk.u;
    }
  }
}

// ---------------------------------------------------------------------------
// Flash attention, DOUBLE-Q: block = 4 waves x 32 q rows = 128 q rows.
// Each wave owns two 16-row q-groups (A: +0..15, B: +16..31); every K/V
// LDS fragment is read ONCE and feeds TWO MFMAs -> LDS bytes per q-row
// halve vs round 6 (the measured per-CU bottleneck).
// ~430 VGPR -> 1 wave/SIMD; ILP (4 QK chains, 32-deep PV) hides latency.
// Unit = (tp, b, r) over CC-tile kv chunks. Rt==1 -> direct fp32 write.
// Rt>=2 -> O' fp16 1KB/q-row, self-hosted: r=0,1 right-half KBs of own
// out-row; r=2,3 left-half KBs; r>=4 ws (128-row slots).
// ---------------------------------------------------------------------------
__global__ __launch_bounds__(256, 1)
void attn_kernel(const char* __restrict__ PREP, const float* __restrict__ Qg,
                 char* __restrict__ wsOp, float* __restrict__ MLp,
                 float* __restrict__ Out, int CC, int TU, int WSB)
{
  __shared__ char smem[2][32768];   // [K 16KB][VT 16KB] per buffer

  const int tid = threadIdx.x;
  const int ln  = tid & 63;
  const int w   = tid >> 6;
  const int m   = ln & 15;
  const int g   = ln >> 4;

  // ---- decode blockIdx -> (tp, b, r), tp descending, b fastest --------------
  int tp = 0, b = 0, r = 0;
  {
    int u = blockIdx.x, base = 0;
    for (int tt = NTP - 1; tt >= 0; --tt) {
      int rt = rt2(tt, CC);
      int cnt = BB * rt;
      if (u < base + cnt) { int loc = u - base; tp = tt; r = loc / BB; b = loc % BB; break; }
      base += cnt;
    }
  }
  const int Rt     = rt2(tp, CC);
  const int direct = (Rt == 1);

  const int T16 = 8 * (tp + 1);
  const int j0  = r * CC;
  const int j1  = min(j0 + CC, T16);
  const int nt  = j1 - j0;

  const int qrowA = tp * 128 + w * 32 + m;
  const int qrowB = qrowA + 16;
  const int qmaxw = tp * 128 + w * 32 + 31;

  // ---- Q fp32 -> fp16 fragments for both groups -----------------------------
  f16x8 qfA[16], qfB[16];
  {
    const float* qpA = Qg + ((size_t)(b * SS + qrowA)) * DD + g * 8;
    const float* qpB = Qg + ((size_t)(b * SS + qrowB)) * DD + g * 8;
    #pragma unroll
    for (int ks = 0; ks < 16; ++ks) {
      float4 a0 = *(const float4*)(qpA + ks * 32);
      float4 a1 = *(const float4*)(qpA + ks * 32 + 4);
      f16x8 v;
      v[0] = (_Float16)a0.x; v[1] = (_Float16)a0.y;
      v[2] = (_Float16)a0.z; v[3] = (_Float16)a0.w;
      v[4] = (_Float16)a1.x; v[5] = (_Float16)a1.y;
      v[6] = (_Float16)a1.z; v[7] = (_Float16)a1.w;
      qfA[ks] = v;
      float4 b0 = *(const float4*)(qpB + ks * 32);
      float4 b1 = *(const float4*)(qpB + ks * 32 + 4);
      f16x8 u;
      u[0] = (_Float16)b0.x; u[1] = (_Float16)b0.y;
      u[2] = (_Float16)b0.z; u[3] = (_Float16)b0.w;
      u[4] = (_Float16)b1.x; u[5] = (_Float16)b1.y;
      u[6] = (_Float16)b1.z; u[7] = (_Float16)b1.w;
      qfB[ks] = u;
    }
  }

  f32x4 acc[32][2];                  // [d-tile][q-group]
  {
    f32x4 z = {0.f, 0.f, 0.f, 0.f};
    #pragma unroll
    for (int i = 0; i < 32; ++i) { acc[i][0] = z; acc[i][1] = z; }
  }
  float mA = NEG_BIG, lA = 0.f, mB = NEG_BIG, lB = 0.f;

  const char* tilebase = PREP + (size_t)b * 128 * 32768;

  auto STAGE = [&](int bi, int jt) {
    const char* src = tilebase + (size_t)jt * 32768;
    #pragma unroll
    for (int i = 0; i < 8; ++i) {
      int o = (tid + i * 256) * 16;
      __builtin_amdgcn_global_load_lds((GV*)(src + o), (LV*)(smem[bi] + o),
                                       16, 0, 0);
    }
  };

  STAGE(0, j0);

  const int vs = ((g ^ (m & 3)) & 3) * 16;   // V slot offset (per-lane const)

  for (int jj = 0; jj < nt; ++jj) {
    const int cur = jj & 1;
    __syncthreads();                   // buf[cur] staged (issued last iter)
    if (jj + 1 < nt) STAGE(cur ^ 1, j0 + jj + 1);

    const int kv0 = (j0 + jj) * 16;
    if (kv0 <= qmaxw) {                // causal early-out (wave-uniform)
      const char* kb = smem[cur];

      // ---- QK^T both groups; each K read feeds 2 MFMAs ---------------------
      f32x4 s0A = {0,0,0,0}, s1A = {0,0,0,0}, s0B = {0,0,0,0}, s1B = {0,0,0,0};
      {
        const char* krow = kb + m * 1024;
        const int rsw = (m & 7) << 4;
        __builtin_amdgcn_s_setprio(1);
        #pragma unroll
        for (int kk = 0; kk < 8; ++kk) {
          int offA = ((2 * kk) * 64 + g * 16) ^ rsw;
          int offB = ((2 * kk + 1) * 64 + g * 16) ^ rsw;
          f16x8 ka  = *(const f16x8*)(krow + offA);
          f16x8 kb2 = *(const f16x8*)(krow + offB);
          s0A = __builtin_amdgcn_mfma_f32_16x16x32_f16(ka,  qfA[2 * kk],     s0A, 0, 0, 0);
          s1A = __builtin_amdgcn_mfma_f32_16x16x32_f16(kb2, qfA[2 * kk + 1], s1A, 0, 0, 0);
          s0B = __builtin_amdgcn_mfma_f32_16x16x32_f16(ka,  qfB[2 * kk],     s0B, 0, 0, 0);
          s1B = __builtin_amdgcn_mfma_f32_16x16x32_f16(kb2, qfB[2 * kk + 1], s1B, 0, 0, 0);
        }
        __builtin_amdgcn_s_setprio(0);
      }

      // ---- softmax group A (lane: kv = kv0+4g+e, q = qrowA) ---------------
      f16x4 pfA, pfB;
      {
        float sv0 = (kv0 + 4 * g + 0 <= qrowA) ? (s0A[0] + s1A[0]) : NEG_BIG;
        float sv1 = (kv0 + 4 * g + 1 <= qrowA) ? (s0A[1] + s1A[1]) : NEG_BIG;
        float sv2 = (kv0 + 4 * g + 2 <= qrowA) ? (s0A[2] + s1A[2]) : NEG_BIG;
        float sv3 = (kv0 + 4 * g + 3 <= qrowA) ? (s0A[3] + s1A[3]) : NEG_BIG;
        float tm = fmaxf(fmaxf(sv0, sv1), fmaxf(sv2, sv3));
        tm = fmaxf(tm, __shfl_xor(tm, 16));
        tm = fmaxf(tm, __shfl_xor(tm, 32));
        float sc = 1.f;
        if (__ballot(tm > mA + RESC_THR)) {
          float mnew = fmaxf(mA, tm);
          sc = __expf(mA - mnew);
          mA = mnew;
          #pragma unroll
          for (int i = 0; i < 32; ++i) {
            acc[i][0][0] *= sc; acc[i][0][1] *= sc;
            acc[i][0][2] *= sc; acc[i][0][3] *= sc;
          }
        }
        float p0 = (kv0 + 4 * g + 0 <= qrowA) ? __expf(sv0 - mA) : 0.f;
        float p1 = (kv0 + 4 * g + 1 <= qrowA) ? __expf(sv1 - mA) : 0.f;
        float p2 = (kv0 + 4 * g + 2 <= qrowA) ? __expf(sv2 - mA) : 0.f;
        float p3 = (kv0 + 4 * g + 3 <= qrowA) ? __expf(sv3 - mA) : 0.f;
        float rs = p0 + p1 + p2 + p3;
        rs += __shfl_xor(rs, 16);
        rs += __shfl_xor(rs, 32);
        lA = lA * sc + rs;
        pfA[0] = (_Float16)p0; pfA[1] = (_Float16)p1;
        pfA[2] = (_Float16)p2; pfA[3] = (_Float16)p3;
      }
      // ---- softmax group B -------------------------------------------------
      {
        float sv0 = (kv0 + 4 * g + 0 <= qrowB) ? (s0B[0] + s1B[0]) : NEG_BIG;
        float sv1 = (kv0 + 4 * g + 1 <= qrowB) ? (s0B[1] + s1B[1]) : NEG_BIG;
        float sv2 = (kv0 + 4 * g + 2 <= qrowB) ? (s0B[2] + s1B[2]) : NEG_BIG;
        float sv3 = (kv0 + 4 * g + 3 <= qrowB) ? (s0B[3] + s1B[3]) : NEG_BIG;
        float tm = fmaxf(fmaxf(sv0, sv1), fmaxf(sv2, sv3));
        tm = fmaxf(tm, __shfl_xor(tm, 16));
        tm = fmaxf(tm, __shfl_xor(tm, 32));
        float sc = 1.f;
        if (__ballot(tm > mB + RESC_THR)) {
          float mnew = fmaxf(mB, tm);
          sc = __expf(mB - mnew);
          mB = mnew;
          #pragma unroll
          for (int i = 0; i < 32; ++i) {
            acc[i][1][0] *= sc; acc[i][1][1] *= sc;
            acc[i][1][2] *= sc; acc[i][1][3] *= sc;
          }
        }
        float p0 = (kv0 + 4 * g + 0 <= qrowB) ? __expf(sv0 - mB) : 0.f;
        float p1 = (kv0 + 4 * g + 1 <= qrowB) ? __expf(sv1 - mB) : 0.f;
        float p2 = (kv0 + 4 * g + 2 <= qrowB) ? __expf(sv2 - mB) : 0.f;
        float p3 = (kv0 + 4 * g + 3 <= qrowB) ? __expf(sv3 - mB) : 0.f;
        float rs = p0 + p1 + p2 + p3;
        rs += __shfl_xor(rs, 16);
        rs += __shfl_xor(rs, 32);
        lB = lB * sc + rs;
        pfB[0] = (_Float16)p0; pfB[1] = (_Float16)p1;
        pfB[2] = (_Float16)p2; pfB[3] = (_Float16)p3;
      }

      // ---- PV: each V b128 read feeds 4 MFMAs (2 d x 2 q-groups) -----------
      const char* vb = kb + 16384;
      __builtin_amdgcn_s_setprio(1);
      #pragma unroll
      for (int e = 0; e < 16; ++e) {
        f16x8 vv = *(const f16x8*)(vb + e * 1024 + m * 64 + vs);
        f16x4 vlo; vlo[0] = vv[0]; vlo[1] = vv[1]; vlo[2] = vv[2]; vlo[3] = vv[3];
        f16x4 vhi; vhi[0] = vv[4]; vhi[1] = vv[5]; vhi[2] = vv[6]; vhi[3] = vv[7];
        acc[2 * e][0]     = __builtin_amdgcn_mfma_f32_16x16x16f16(vlo, pfA, acc[2 * e][0],     0, 0, 0);
        acc[2 * e + 1][0] = __builtin_amdgcn_mfma_f32_16x16x16f16(vhi, pfA, acc[2 * e + 1][0], 0, 0, 0);
        acc[2 * e][1]     = __builtin_amdgcn_mfma_f32_16x16x16f16(vlo, pfB, acc[2 * e][1],     0, 0, 0);
        acc[2 * e + 1][1] = __builtin_amdgcn_mfma_f32_16x16x16f16(vhi, pfB, acc[2 * e + 1][1], 0, 0, 0);
      }
      __builtin_amdgcn_s_setprio(0);
    }
  }

  // ---- epilogue -------------------------------------------------------------
  int uoff = 0, wsoff = 0;
  if (!direct) {
    for (int tt = 0; tt < tp; ++tt) {
      int rtt = rt2(tt, CC);
      if (rtt >= 2) uoff += rtt;
      if (rtt > 4)  wsoff += rtt - 4;
    }
  }

  #pragma unroll
  for (int h = 0; h < 2; ++h) {
    const int qloc = w * 32 + h * 16 + m;
    const int qrow = tp * 128 + qloc;
    const float mst = h ? mB : mA;
    const float lst = h ? lB : lA;

    if (direct) {
      float inv = 1.0f / lst;
      float* orow = Out + ((size_t)(b * SS + qrow)) * 1024 + 512;
      #pragma unroll
      for (int dt = 0; dt < 32; ++dt) {
        float4 v4;
        v4.x = acc[dt][h][0] * inv; v4.y = acc[dt][h][1] * inv;
        v4.z = acc[dt][h][2] * inv; v4.w = acc[dt][h][3] * inv;
        *(float4*)(orow + dt * 16 + g * 4) = v4;
      }
    } else {
      if (ln < 16) {
        float* mlp = MLp + ((size_t)(b * TU + uoff + r) * 128 + qloc) * 2;
        mlp[0] = mst; mlp[1] = lst;
      }
      char* rowb;
      if (r < 4) {
        int hoff = (r & 2) ? ((r & 1) * 1024) : (2048 + (r & 1) * 1024);
        rowb = (char*)Out + (size_t)(b * SS + qrow) * 4096 + hoff;
      } else {
        rowb = wsOp + ((size_t)(b * WSB + wsoff + (r - 4)) * 128 + qloc) * 1024;
      }
      #pragma unroll
      for (int dt = 0; dt < 32; ++dt) {
        PK4 p;
        p.h[0] = (_Float16)acc[dt][h][0]; p.h[1] = (_Float16)acc[dt][h][1];
        p.h[2] = (_Float16)acc[dt][h][2]; p.h[3] = (_Float16)acc[dt][h][3];
        *(uint2*)(rowb + dt * 32 + g * 8) = p.u;
      }
    }
  }
}

// ---------------------------------------------------------------------------
// Fused combine + orig copy (round-6 scheme, 128-row units). One wave per
// output row; reads hosted partials from its own row bytes + ws, merges,
// writes right half (merged) and left half (orig).
// ---------------------------------------------------------------------------
__global__ __launch_bounds__(256)
void combine_kernel(const char* __restrict__ wsOp, const float* __restrict__ MLp,
                    const float* __restrict__ orig, float* Out,
                    int CC, int TU, int WSB)
{
  const int row = blockIdx.x * 4 + (threadIdx.x >> 6);
  const int ln  = threadIdx.x & 63;
  const int b = row >> 11;
  const int s = row & 2047;
  const int tp = s >> 7;
  const int q = s & 127;
  const int c0 = ln * 8;

  const float* op = orig + (size_t)row * 512 + c0;
  float4 og0 = *(const float4*)op;
  float4 og1 = *(const float4*)(op + 4);

  const int Rt = rt2(tp, CC);
  if (Rt >= 2) {
    int uoff = 0, wsoff = 0;
    for (int tt = 0; tt < tp; ++tt) {
      int rtt = rt2(tt, CC);
      if (rtt >= 2) uoff += rtt;
      if (rtt > 4)  wsoff += rtt - 4;
    }
    float mr[MAXR], lr[MAXR];
    #pragma unroll
    for (int rr = 0; rr < MAXR; ++rr) { mr[rr] = NEG_BIG; lr[rr] = 0.f; }
    #pragma unroll
    for (int rr = 0; rr < MAXR; ++rr) {
      if (rr < Rt) {
        const float* p = MLp + ((size_t)(b * TU + uoff + rr) * 128 + q) * 2;
        mr[rr] = p[0]; lr[rr] = p[1];
      }
    }
    float M = NEG_BIG;
    #pragma unroll
    for (int rr = 0; rr < MAXR; ++rr) M = fmaxf(M, mr[rr]);

    float L = 0.f;
    float o[8];
    #pragma unroll
    for (int e = 0; e < 8; ++e) o[e] = 0.f;

    #pragma unroll
    for (int rr = 0; rr < MAXR; ++rr) {
      if (rr < Rt) {
        float wgt = __expf(mr[rr] - M);
        L += wgt * lr[rr];
        const char* sp;
        if (rr < 4) {
          int hoff = (rr & 2) ? ((rr & 1) * 1024) : (2048 + (rr & 1) * 1024);
          sp = (const char*)Out + (size_t)row * 4096 + hoff + c0 * 2;
        } else {
          sp = wsOp + ((size_t)(b * WSB + wsoff + (rr - 4)) * 128 + q) * 1024 + c0 * 2;
        }
        f16x8 v = *(const f16x8*)sp;
        #pragma unroll
        for (int e = 0; e < 8; ++e) o[e] += wgt * (float)v[e];
      }
    }
    float inv = 1.0f / L;
    float4 r0, r1;
    r0.x = o[0] * inv; r0.y = o[1] * inv; r0.z = o[2] * inv; r0.w = o[3] * inv;
    r1.x = o[4] * inv; r1.y = o[5] * inv; r1.z = o[6] * inv; r1.w = o[7] * inv;
    *(float4*)(Out + (size_t)row * 1024 + 512 + c0)     = r0;
    *(float4*)(Out + (size_t)row * 1024 + 512 + c0 + 4) = r1;
  }
  // left half: original (overwrites hosted r=2,3 bytes AFTER the reads above)
  *(float4*)(Out + (size_t)row * 1024 + c0)     = og0;
  *(float4*)(Out + (size_t)row * 1024 + c0 + 4) = og1;
}

extern "C" void kernel_launch(void* const* d_in, const int* in_sizes, int n_in,
                              void* d_out, int out_size, void* d_ws, size_t ws_size,
                              hipStream_t stream)
{
  (void)in_sizes; (void)n_in; (void)out_size;
  const float* keys     = (const float*)d_in[0];
  const float* queries  = (const float*)d_in[1];
  const float* values   = (const float*)d_in[2];
  const float* original = (const float*)d_in[3];
  float* out = (float*)d_out;

  const size_t PREPB = (size_t)BB * 128 * 32768;   // 16,777,216

  // Tier ladder over 128-row q-units. need = PREP + ML(BB*TU*1KB) +
  // ws O' slots (BB*WSB*128KB). CC=20: TU=59, WSB=11 -> ~22.8MB (fits
  // proven ws floor 31.57MB); grid 244 blocks ~ 1/CU.
  const int CCcand[5] = {20, 24, 32, 48, 128};
  int CC = 128, TU = 0, WSB = 0, units = NTP;
  for (int i = 0; i < 5; ++i) {
    int cc = CCcand[i];
    int tu = 0, wsb = 0, un = 0;
    for (int t = 0; t < NTP; ++t) {
      int rt = rt2(t, cc);
      un += rt;
      if (rt >= 2) tu += rt;
      if (rt > 4)  wsb += rt - 4;
    }
    size_t need = PREPB + (size_t)BB * tu * 1024 + (size_t)BB * wsb * 131072;
    if (ws_size >= need) { CC = cc; TU = tu; WSB = wsb; units = un; break; }
  }

  char* PREP = (char*)d_ws;
  float* MLp = (float*)(PREP + PREPB);
  char* wsOp = PREP + PREPB + (size_t)BB * TU * 1024;

  hipLaunchKernelGGL(prep_kernel, dim3(BB * 128), dim3(256), 0, stream,
                     keys, values, PREP);

  hipLaunchKernelGGL(attn_kernel, dim3(BB * units), dim3(256), 0, stream,
                     PREP, queries, wsOp, MLp, out, CC, TU, WSB);

  hipLaunchKernelGGL(combine_kernel, dim3((BB * SS) / 4), dim3(256), 0, stream,
                     wsOp, MLp, original, out, CC, TU, WSB);
}

// Round 12
// 96.638 us; speedup vs baseline: 3.7419x; 3.7419x over previous
//
#include <hip/hip_runtime.h>
#include <stdint.h>

#define BB 4
#define SS 2048
#define DD 512
#define NTQ 32            // S/64 q-tiles per batch
#define NEG_BIG -1e30f
#define RESC_THR 4.0f     // defer-max threshold
#define CAPOUT 256        // O' slots that fit in out[...,0:512] halves

typedef __attribute__((ext_vector_type(4))) float f32x4;
typedef __attribute__((ext_vector_type(8))) _Float16 f16x8;
typedef __attribute__((ext_vector_type(4))) _Float16 f16x4;

typedef __attribute__((address_space(1))) void GV;
typedef __attribute__((address_space(3))) void LV;

union PK4 { _Float16 h[4]; uint2 u; };

// chunks per q-tile t for chunk size CC (in 16-kv tiles)
__device__ __host__ __forceinline__ int rt_of(int t, int CC) {
  return (4 * (t + 1) + CC - 1) / CC;
}

// O' slot location: first CAPOUT slots live in the out[...,0:512] halves
// (32 rows x 2KB, chunk stride 4096B); the rest in ws (contiguous, stride 2048).
__device__ __forceinline__ char* slot_base(float* Out, char* wsOp, int s, int& stride) {
  if (s < CAPOUT) { stride = 4096; return (char*)Out + (size_t)s * 131072; }
  stride = 2048;  return wsOp + (size_t)(s - CAPOUT) * 65536;
}

// ---------------------------------------------------------------------------
// Prep: K -> fp16 tile images in exact LDS byte layout (XOR swizzle baked in),
//       V -> pair-transposed fp16 images. One (b, 16-kv-tile) per block.
// K image:  byte = rr*1024 + ((cc*2) ^ ((rr&7)<<4))
// V image:  d -> e=d>>5, mm=d&15, p=(d>>4)&1;
//           byte = 16384 + e*1024 + mm*64 + ((kq4^(mm&3))&3)*16 + p*8
// ---------------------------------------------------------------------------
__global__ __launch_bounds__(256)
void prep_kernel(const float* __restrict__ K, const float* __restrict__ V,
                 char* __restrict__ PREP)
{
  const int blk = blockIdx.x;
  const int b   = blk >> 7;
  const int j   = blk & 127;
  const int tid = threadIdx.x;
  char* img = PREP + (size_t)blk * 32768;

  #pragma unroll
  for (int i = 0; i < 8; ++i) {
    int chunk = tid + 256 * i;
    int rr = chunk >> 7;
    int cc = (chunk & 127) << 2;
    float4 a = *(const float4*)(K + ((size_t)(b * SS + j * 16 + rr)) * DD + cc);
    PK4 p; p.h[0] = (_Float16)a.x; p.h[1] = (_Float16)a.y;
           p.h[2] = (_Float16)a.z; p.h[3] = (_Float16)a.w;
    int off = rr * 1024 + ((cc * 2) ^ ((rr & 7) << 4));
    *(uint2*)(img + off) = p.u;
  }

  #pragma unroll
  for (int half = 0; half < 2; ++half) {
    int d = tid + 256 * half;
    const float* vp = V + ((size_t)(b * SS + j * 16)) * DD + d;
    int e = d >> 5, mm = d & 15, p = (d >> 4) & 1;
    #pragma unroll
    for (int kq4 = 0; kq4 < 4; ++kq4) {
      PK4 pk;
      pk.h[0] = (_Float16)vp[(kq4 * 4 + 0) * DD];
      pk.h[1] = (_Float16)vp[(kq4 * 4 + 1) * DD];
      pk.h[2] = (_Float16)vp[(kq4 * 4 + 2) * DD];
      pk.h[3] = (_Float16)vp[(kq4 * 4 + 3) * DD];
      int slot = (kq4 ^ (mm & 3)) & 3;
      *(uint2*)(img + 16384 + e * 1024 + mm * 64 + slot * 16 + p * 8) = pk.u;
    }
  }
}

// ---------------------------------------------------------------------------
// Flash attention over fixed-size kv chunks (CC 16-row tiles per chunk).
// Unit = (t, b, r); decode order: t desc (longest first), r, then b fastest.
// Rt==1 units write normalized fp32 output directly; Rt>=2 write (O', m, l)
// to slot b*TSLOT + OFF(t) + r (slots live in out-left-halves then ws).
// PROVEN 64.2us inner loop (round 6 bench) — do not touch.
// ---------------------------------------------------------------------------
__global__ __launch_bounds__(256, 2)
void attn_kernel(const char* __restrict__ PREP, const float* __restrict__ Qg,
                 char* __restrict__ wsOp, float* __restrict__ MLp,
                 float* __restrict__ Out, int CC, int TSLOT)
{
  __shared__ char smem[2][32768];   // [K 16KB][VT 16KB] per buffer

  const int tid = threadIdx.x;
  const int ln  = tid & 63;
  const int w   = tid >> 6;
  const int m   = ln & 15;
  const int g   = ln >> 4;

  // ---- decode blockIdx -> (t, b, r), t descending, b fastest ----------------
  int t = 0, b = 0, r = 0;
  {
    int u = blockIdx.x, base = 0;
    for (int tt = NTQ - 1; tt >= 0; --tt) {
      int rt = rt_of(tt, CC);
      int cnt = BB * rt;
      if (u < base + cnt) { int loc = u - base; t = tt; r = loc / BB; b = loc % BB; break; }
      base += cnt;
    }
  }
  const int Rt     = rt_of(t, CC);
  const int direct = (Rt == 1);

  const int T16 = 4 * (t + 1);
  const int j0  = r * CC;
  const int j1  = min(j0 + CC, T16);
  const int nt  = j1 - j0;          // >= 1 by construction

  int slot = 0;
  if (!direct) {
    int off = 0;
    for (int tt = 0; tt < t; ++tt) {
      int rt = rt_of(tt, CC);
      if (rt >= 2) off += rt;
    }
    slot = b * TSLOT + off + r;
  }

  const int qrow  = t * 64 + w * 16 + m;
  const int qmaxw = t * 64 + w * 16 + 15;

  // ---- Q fp32 -> fp16 fragments (once per block) ---------------------------
  f16x8 qf[16];
  {
    const float* qp = Qg + ((size_t)(b * SS + qrow)) * DD + g * 8;
    #pragma unroll
    for (int ks = 0; ks < 16; ++ks) {
      float4 a0 = *(const float4*)(qp + ks * 32);
      float4 a1 = *(const float4*)(qp + ks * 32 + 4);
      f16x8 v;
      v[0] = (_Float16)a0.x; v[1] = (_Float16)a0.y;
      v[2] = (_Float16)a0.z; v[3] = (_Float16)a0.w;
      v[4] = (_Float16)a1.x; v[5] = (_Float16)a1.y;
      v[6] = (_Float16)a1.z; v[7] = (_Float16)a1.w;
      qf[ks] = v;
    }
  }

  f32x4 acc[32];
  {
    f32x4 z = {0.f, 0.f, 0.f, 0.f};
    #pragma unroll
    for (int i = 0; i < 32; ++i) acc[i] = z;
  }
  float mst = NEG_BIG, lst = 0.f;

  const char* tilebase = PREP + (size_t)b * 128 * 32768;

  auto STAGE = [&](int bi, int jt) {
    const char* src = tilebase + (size_t)jt * 32768;
    #pragma unroll
    for (int i = 0; i < 8; ++i) {
      int o = (tid + i * 256) * 16;
      __builtin_amdgcn_global_load_lds((GV*)(src + o), (LV*)(smem[bi] + o),
                                       16, 0, 0);
    }
  };

  STAGE(0, j0);

  const int vs = ((g ^ (m & 3)) & 3) * 16;   // V slot offset (per-lane const)

  for (int jj = 0; jj < nt; ++jj) {
    const int cur = jj & 1;
    __syncthreads();                       // buf[cur] staged (issued last iter)
    if (jj + 1 < nt) STAGE(cur ^ 1, j0 + jj + 1);

    const int kv0 = (j0 + jj) * 16;
    if (kv0 <= qmaxw) {                    // causal early-out (wave-uniform)
      const char* kb = smem[cur];

      // ---- QK^T: S^T[kv][q], fp16, split accumulators ----------------------
      f32x4 s0 = {0.f, 0.f, 0.f, 0.f};
      f32x4 s1 = {0.f, 0.f, 0.f, 0.f};
      {
        const char* krow = kb + m * 1024;
        const int rsw = (m & 7) << 4;
        __builtin_amdgcn_s_setprio(1);
        #pragma unroll
        for (int kk = 0; kk < 8; ++kk) {
          int offA = ((2 * kk) * 64 + g * 16) ^ rsw;
          int offB = ((2 * kk + 1) * 64 + g * 16) ^ rsw;
          f16x8 ka = *(const f16x8*)(krow + offA);
          f16x8 kb2 = *(const f16x8*)(krow + offB);
          s0 = __builtin_amdgcn_mfma_f32_16x16x32_f16(ka,  qf[2 * kk],     s0, 0, 0, 0);
          s1 = __builtin_amdgcn_mfma_f32_16x16x32_f16(kb2, qf[2 * kk + 1], s1, 0, 0, 0);
        }
        __builtin_amdgcn_s_setprio(0);
      }
      f32x4 s;
      s[0] = s0[0] + s1[0]; s[1] = s0[1] + s1[1];
      s[2] = s0[2] + s1[2]; s[3] = s0[3] + s1[3];

      // ---- online softmax (lane: kv = kv0+4g+e, q = qrow) -----------------
      float sv0 = (kv0 + 4 * g + 0 <= qrow) ? s[0] : NEG_BIG;
      float sv1 = (kv0 + 4 * g + 1 <= qrow) ? s[1] : NEG_BIG;
      float sv2 = (kv0 + 4 * g + 2 <= qrow) ? s[2] : NEG_BIG;
      float sv3 = (kv0 + 4 * g + 3 <= qrow) ? s[3] : NEG_BIG;
      float tm = fmaxf(fmaxf(sv0, sv1), fmaxf(sv2, sv3));
      tm = fmaxf(tm, __shfl_xor(tm, 16));
      tm = fmaxf(tm, __shfl_xor(tm, 32));

      float sc = 1.f;
      unsigned long long need = __ballot(tm > mst + RESC_THR);
      if (need) {                          // wave-uniform, rare (defer-max)
        float mnew = fmaxf(mst, tm);
        sc = __expf(mst - mnew);
        mst = mnew;
        #pragma unroll
        for (int i = 0; i < 32; ++i) {
          acc[i][0] *= sc; acc[i][1] *= sc; acc[i][2] *= sc; acc[i][3] *= sc;
        }
      }
      float p0 = (kv0 + 4 * g + 0 <= qrow) ? __expf(sv0 - mst) : 0.f;
      float p1 = (kv0 + 4 * g + 1 <= qrow) ? __expf(sv1 - mst) : 0.f;
      float p2 = (kv0 + 4 * g + 2 <= qrow) ? __expf(sv2 - mst) : 0.f;
      float p3 = (kv0 + 4 * g + 3 <= qrow) ? __expf(sv3 - mst) : 0.f;
      float rs = p0 + p1 + p2 + p3;
      rs += __shfl_xor(rs, 16);
      rs += __shfl_xor(rs, 32);
      lst = lst * sc + rs;

      // ---- PV: O^T += V^T * P^T; paired b128 V reads feed 2 MFMAs ---------
      f16x4 pf;
      pf[0] = (_Float16)p0; pf[1] = (_Float16)p1;
      pf[2] = (_Float16)p2; pf[3] = (_Float16)p3;
      const char* vb = kb + 16384;
      __builtin_amdgcn_s_setprio(1);
      #pragma unroll
      for (int e = 0; e < 16; ++e) {
        f16x8 vv = *(const f16x8*)(vb + e * 1024 + m * 64 + vs);
        f16x4 vlo; vlo[0] = vv[0]; vlo[1] = vv[1]; vlo[2] = vv[2]; vlo[3] = vv[3];
        f16x4 vhi; vhi[0] = vv[4]; vhi[1] = vv[5]; vhi[2] = vv[6]; vhi[3] = vv[7];
        acc[2 * e]     = __builtin_amdgcn_mfma_f32_16x16x16f16(vlo, pf, acc[2 * e],     0, 0, 0);
        acc[2 * e + 1] = __builtin_amdgcn_mfma_f32_16x16x16f16(vhi, pf, acc[2 * e + 1], 0, 0, 0);
      }
      __builtin_amdgcn_s_setprio(0);
    }
  }

  // ---- epilogue -------------------------------------------------------------
  const int q = w * 16 + m;
  if (direct) {
    float inv = 1.0f / lst;
    float* orow = Out + ((size_t)(b * SS + qrow)) * 1024 + 512;
    #pragma unroll
    for (int dt = 0; dt < 32; ++dt) {
      float4 v4;
      v4.x = acc[dt][0] * inv; v4.y = acc[dt][1] * inv;
      v4.z = acc[dt][2] * inv; v4.w = acc[dt][3] * inv;
      *(float4*)(orow + dt * 16 + g * 4) = v4;
    }
  } else {
    if (ln < 16) {
      float* mlp = MLp + ((size_t)slot * 64 + q) * 2;
      mlp[0] = mst; mlp[1] = lst;
    }
    int stride; char* sb = slot_base(Out, wsOp, slot, stride);
    char* rowb = sb + (size_t)(q >> 1) * stride + (q & 1) * 1024;
    #pragma unroll
    for (int dt = 0; dt < 32; ++dt) {
      PK4 p;
      p.h[0] = (_Float16)acc[dt][0]; p.h[1] = (_Float16)acc[dt][1];
      p.h[2] = (_Float16)acc[dt][2]; p.h[3] = (_Float16)acc[dt][3];
      *(uint2*)(rowb + dt * 32 + g * 8) = p.u;
    }
  }
}

// ---------------------------------------------------------------------------
// Combine: merges partial (O', m, l) for q-tiles with Rt >= 2 and writes
// out[...,512:1024]. Does NOT touch out[...,0:512] (slots may live there);
// copy_orig runs after and fills the left halves.
// ---------------------------------------------------------------------------
__global__ __launch_bounds__(256)
void combine_kernel(char* __restrict__ wsOp, const float* __restrict__ MLp,
                    float* __restrict__ Out, int CC, int TSLOT)
{
  int gid = blockIdx.x * 256 + threadIdx.x;
  int row = gid >> 7;
  int c4  = (gid & 127) << 2;
  int b = row >> 11;
  int s = row & 2047;
  int t = s >> 6;
  int qloc = s & 63;

  const int Rt = rt_of(t, CC);
  if (Rt < 2) return;                       // direct-written by attn_kernel

  int off = 0;
  for (int tt = 0; tt < t; ++tt) {
    int rt = rt_of(tt, CC);
    if (rt >= 2) off += rt;
  }
  const int base = b * TSLOT + off;

  float mr[8], lr[8];
  #pragma unroll
  for (int rr = 0; rr < 8; ++rr) { mr[rr] = NEG_BIG; lr[rr] = 0.f; }
  #pragma unroll
  for (int rr = 0; rr < 8; ++rr) {
    if (rr < Rt) {
      const float* p = MLp + ((size_t)(base + rr) * 64 + qloc) * 2;
      mr[rr] = p[0]; lr[rr] = p[1];
    }
  }
  float M = NEG_BIG;
  #pragma unroll
  for (int rr = 0; rr < 8; ++rr) M = fmaxf(M, mr[rr]);

  float L = 0.f, a0 = 0.f, a1 = 0.f, a2 = 0.f, a3 = 0.f;
  #pragma unroll
  for (int rr = 0; rr < 8; ++rr) {
    if (rr < Rt && mr[rr] > -5e29f) {       // skip rows empty in this chunk
      float wgt = __expf(mr[rr] - M);
      L += wgt * lr[rr];
      int stride; char* sb = slot_base(Out, wsOp, base + rr, stride);
      const char* op = sb + (size_t)(qloc >> 1) * stride + (qloc & 1) * 1024 + c4 * 2;
      f16x4 ov = *(const f16x4*)op;
      a0 += wgt * (float)ov[0]; a1 += wgt * (float)ov[1];
      a2 += wgt * (float)ov[2]; a3 += wgt * (float)ov[3];
    }
  }
  float inv = 1.0f / L;
  float4 r4; r4.x = a0 * inv; r4.y = a1 * inv; r4.z = a2 * inv; r4.w = a3 * inv;
  *(float4*)(Out + (size_t)row * 1024 + 512 + c4) = r4;
}

__global__ __launch_bounds__(256)
void copy_orig(const float* __restrict__ orig, float* __restrict__ Out)
{
  int gid = blockIdx.x * 256 + threadIdx.x;
  int row = gid >> 7;
  int c4  = (gid & 127) << 2;
  *(float4*)(Out + (size_t)row * 1024 + c4) = *(const float4*)(orig + (size_t)row * 512 + c4);
}

extern "C" void kernel_launch(void* const* d_in, const int* in_sizes, int n_in,
                              void* d_out, int out_size, void* d_ws, size_t ws_size,
                              hipStream_t stream)
{
  (void)in_sizes; (void)n_in; (void)out_size;
  const float* keys     = (const float*)d_in[0];
  const float* queries  = (const float*)d_in[1];
  const float* values   = (const float*)d_in[2];
  const float* original = (const float*)d_in[3];
  float* out = (float*)d_out;

  const size_t PREPB = (size_t)BB * 128 * 32768;   // 16,777,216
  const size_t MLRES = 512 * 512;                  // 262,144 (<=512 slots x 512B)

  // slot capacity: 256 slots hidden in out[...,0:512] + whatever ws holds
  long nWs = (ws_size > PREPB + MLRES) ? (long)((ws_size - PREPB - MLRES) / 65536) : 0;
  long cap = CAPOUT + nWs;

  // Ladder refined vs round 6: CC=21 needs 444 slots <= 445 proven cap ->
  // chain 24 -> 21 (attn was exactly chain-bound at 2.68us/tile).
  const int CCcand[8] = {20, 21, 22, 24, 32, 48, 64, 128};
  int CC = 128, TSLOT = 0, units = NTQ;
  for (int i = 0; i < 8; ++i) {
    int cc = CCcand[i];
    int un = 0, sl = 0;
    for (int t = 0; t < NTQ; ++t) {
      int rt = rt_of(t, cc);
      un += rt;
      if (rt >= 2) sl += rt;
    }
    long total = (long)BB * sl;
    if (total <= cap && total <= 512) { CC = cc; TSLOT = sl; units = un; break; }
  }

  char* PREP = (char*)d_ws;
  float* MLp = (float*)(PREP + PREPB);
  char* wsOp = PREP + PREPB + MLRES;

  hipLaunchKernelGGL(prep_kernel, dim3(BB * 128), dim3(256), 0, stream,
                     keys, values, PREP);

  hipLaunchKernelGGL(attn_kernel, dim3(BB * units), dim3(256), 0, stream,
                     PREP, queries, wsOp, MLp, out, CC, TSLOT);

  const int cgrid = (BB * SS * 128) / 256;   // 4096 blocks
  hipLaunchKernelGGL(combine_kernel, dim3(cgrid), dim3(256), 0, stream,
                     wsOp, MLp, out, CC, TSLOT);
  hipLaunchKernelGGL(copy_orig, dim3(cgrid), dim3(256), 0, stream, original, out);
}

// Round 13
// 85.563 us; speedup vs baseline: 4.2263x; 1.1294x over previous
//
#include <hip/hip_runtime.h>
#include <stdint.h>

#define BB 4
#define SS 2048
#define DD 512
#define NTQ 32            // S/64 q-tiles per batch
#define NEG_BIG -1e30f
#define RESC_THR 4.0f     // defer-max threshold
#define MAXR 12           // max chunks per q-tile across tiers

typedef __attribute__((ext_vector_type(4))) float f32x4;
typedef __attribute__((ext_vector_type(8))) _Float16 f16x8;
typedef __attribute__((ext_vector_type(4))) _Float16 f16x4;

typedef __attribute__((address_space(1))) void GV;
typedef __attribute__((address_space(3))) void LV;

union PK4 { _Float16 h[4]; uint2 u; };

// chunks per q-tile t for chunk size CC (in 16-kv tiles)
__device__ __host__ __forceinline__ int rt_of(int t, int CC) {
  return (4 * (t + 1) + CC - 1) / CC;
}

// ---------------------------------------------------------------------------
// Prep: K -> fp16 tile images in exact LDS byte layout (XOR swizzle baked in),
//       V -> pair-transposed fp16 images. One (b, 16-kv-tile) per block.
// (byte-identical to round 6 — verified)
// ---------------------------------------------------------------------------
__global__ __launch_bounds__(256)
void prep_kernel(const float* __restrict__ K, const float* __restrict__ V,
                 char* __restrict__ PREP)
{
  const int blk = blockIdx.x;
  const int b   = blk >> 7;
  const int j   = blk & 127;
  const int tid = threadIdx.x;
  char* img = PREP + (size_t)blk * 32768;

  #pragma unroll
  for (int i = 0; i < 8; ++i) {
    int chunk = tid + 256 * i;
    int rr = chunk >> 7;
    int cc = (chunk & 127) << 2;
    float4 a = *(const float4*)(K + ((size_t)(b * SS + j * 16 + rr)) * DD + cc);
    PK4 p; p.h[0] = (_Float16)a.x; p.h[1] = (_Float16)a.y;
           p.h[2] = (_Float16)a.z; p.h[3] = (_Float16)a.w;
    int off = rr * 1024 + ((cc * 2) ^ ((rr & 7) << 4));
    *(uint2*)(img + off) = p.u;
  }

  #pragma unroll
  for (int half = 0; half < 2; ++half) {
    int d = tid + 256 * half;
    const float* vp = V + ((size_t)(b * SS + j * 16)) * DD + d;
    int e = d >> 5, mm = d & 15, p = (d >> 4) & 1;
    #pragma unroll
    for (int kq4 = 0; kq4 < 4; ++kq4) {
      PK4 pk;
      pk.h[0] = (_Float16)vp[(kq4 * 4 + 0) * DD];
      pk.h[1] = (_Float16)vp[(kq4 * 4 + 1) * DD];
      pk.h[2] = (_Float16)vp[(kq4 * 4 + 2) * DD];
      pk.h[3] = (_Float16)vp[(kq4 * 4 + 3) * DD];
      int slot = (kq4 ^ (mm & 3)) & 3;
      *(uint2*)(img + 16384 + e * 1024 + mm * 64 + slot * 16 + p * 8) = pk.u;
    }
  }
}

// ---------------------------------------------------------------------------
// Flash attention over fixed-size kv chunks (CC 16-row tiles per chunk).
// Unit = (t, b, r). Rt==1 units write normalized output directly.
// Rt>=2 units write O' (fp16, 1KB per q-row) to SELF-HOSTED slots:
//   r=0 -> out-row[q] bytes [2048,3072)   r=1 -> [3072,4096)
//   r=2 -> out-row[q] bytes [0,1024)      r=3 -> [1024,2048)
//   r>=4 -> ws slot (b*WSB + wsoff(t) + r-4)
// so each out-row hosts only ITS OWN q-row's partials -> combine is
// row-self-contained and can write both halves (no copy_orig kernel).
// Scheduling rules (R7/R12 analysis): grid <= 512 (all-resident);
// makespan = max chain x ~3.2us/tile; CC=19 is the provable chain floor.
// ---------------------------------------------------------------------------
__global__ __launch_bounds__(256, 2)
void attn_kernel(const char* __restrict__ PREP, const float* __restrict__ Qg,
                 char* __restrict__ wsOp, float* __restrict__ MLp,
                 float* __restrict__ Out, int CC, int TU, int WSB)
{
  __shared__ char smem[2][32768];   // [K 16KB][VT 16KB] per buffer

  const int tid = threadIdx.x;
  const int ln  = tid & 63;
  const int w   = tid >> 6;
  const int m   = ln & 15;
  const int g   = ln >> 4;

  // ---- decode blockIdx -> (t, b, r), t descending, b fastest ----------------
  int t = 0, b = 0, r = 0;
  {
    int u = blockIdx.x, base = 0;
    for (int tt = NTQ - 1; tt >= 0; --tt) {
      int rt = rt_of(tt, CC);
      int cnt = BB * rt;
      if (u < base + cnt) { int loc = u - base; t = tt; r = loc / BB; b = loc % BB; break; }
      base += cnt;
    }
  }
  const int Rt     = rt_of(t, CC);
  const int direct = (Rt == 1);

  const int T16 = 4 * (t + 1);
  const int j0  = r * CC;
  const int j1  = min(j0 + CC, T16);
  const int nt  = j1 - j0;          // >= 1 by construction

  const int qrow  = t * 64 + w * 16 + m;
  const int qmaxw = t * 64 + w * 16 + 15;

  // ---- Q fp32 -> fp16 fragments (once per block) ---------------------------
  f16x8 qf[16];
  {
    const float* qp = Qg + ((size_t)(b * SS + qrow)) * DD + g * 8;
    #pragma unroll
    for (int ks = 0; ks < 16; ++ks) {
      float4 a0 = *(const float4*)(qp + ks * 32);
      float4 a1 = *(const float4*)(qp + ks * 32 + 4);
      f16x8 v;
      v[0] = (_Float16)a0.x; v[1] = (_Float16)a0.y;
      v[2] = (_Float16)a0.z; v[3] = (_Float16)a0.w;
      v[4] = (_Float16)a1.x; v[5] = (_Float16)a1.y;
      v[6] = (_Float16)a1.z; v[7] = (_Float16)a1.w;
      qf[ks] = v;
    }
  }

  f32x4 acc[32];
  {
    f32x4 z = {0.f, 0.f, 0.f, 0.f};
    #pragma unroll
    for (int i = 0; i < 32; ++i) acc[i] = z;
  }
  float mst = NEG_BIG, lst = 0.f;

  const char* tilebase = PREP + (size_t)b * 128 * 32768;

  auto STAGE = [&](int bi, int jt) {
    const char* src = tilebase + (size_t)jt * 32768;
    #pragma unroll
    for (int i = 0; i < 8; ++i) {
      int o = (tid + i * 256) * 16;
      __builtin_amdgcn_global_load_lds((GV*)(src + o), (LV*)(smem[bi] + o),
                                       16, 0, 0);
    }
  };

  STAGE(0, j0);

  const int vs = ((g ^ (m & 3)) & 3) * 16;   // V slot offset (per-lane const)

  for (int jj = 0; jj < nt; ++jj) {
    const int cur = jj & 1;
    __syncthreads();                       // buf[cur] staged (issued last iter)
    if (jj + 1 < nt) STAGE(cur ^ 1, j0 + jj + 1);

    const int kv0 = (j0 + jj) * 16;
    if (kv0 <= qmaxw) {                    // causal early-out (wave-uniform)
      const char* kb = smem[cur];

      // ---- QK^T: S^T[kv][q], fp16, split accumulators ----------------------
      f32x4 s0 = {0.f, 0.f, 0.f, 0.f};
      f32x4 s1 = {0.f, 0.f, 0.f, 0.f};
      {
        const char* krow = kb + m * 1024;
        const int rsw = (m & 7) << 4;
        __builtin_amdgcn_s_setprio(1);
        #pragma unroll
        for (int kk = 0; kk < 8; ++kk) {
          int offA = ((2 * kk) * 64 + g * 16) ^ rsw;
          int offB = ((2 * kk + 1) * 64 + g * 16) ^ rsw;
          f16x8 ka = *(const f16x8*)(krow + offA);
          f16x8 kb2 = *(const f16x8*)(krow + offB);
          s0 = __builtin_amdgcn_mfma_f32_16x16x32_f16(ka,  qf[2 * kk],     s0, 0, 0, 0);
          s1 = __builtin_amdgcn_mfma_f32_16x16x32_f16(kb2, qf[2 * kk + 1], s1, 0, 0, 0);
        }
        __builtin_amdgcn_s_setprio(0);
      }
      f32x4 s;
      s[0] = s0[0] + s1[0]; s[1] = s0[1] + s1[1];
      s[2] = s0[2] + s1[2]; s[3] = s0[3] + s1[3];

      // ---- online softmax (lane: kv = kv0+4g+e, q = qrow) -----------------
      float sv0 = (kv0 + 4 * g + 0 <= qrow) ? s[0] : NEG_BIG;
      float sv1 = (kv0 + 4 * g + 1 <= qrow) ? s[1] : NEG_BIG;
      float sv2 = (kv0 + 4 * g + 2 <= qrow) ? s[2] : NEG_BIG;
      float sv3 = (kv0 + 4 * g + 3 <= qrow) ? s[3] : NEG_BIG;
      float tm = fmaxf(fmaxf(sv0, sv1), fmaxf(sv2, sv3));
      tm = fmaxf(tm, __shfl_xor(tm, 16));
      tm = fmaxf(tm, __shfl_xor(tm, 32));

      float sc = 1.f;
      unsigned long long need = __ballot(tm > mst + RESC_THR);
      if (need) {                          // wave-uniform, rare (defer-max)
        float mnew = fmaxf(mst, tm);
        sc = __expf(mst - mnew);
        mst = mnew;
        #pragma unroll
        for (int i = 0; i < 32; ++i) {
          acc[i][0] *= sc; acc[i][1] *= sc; acc[i][2] *= sc; acc[i][3] *= sc;
        }
      }
      float p0 = (kv0 + 4 * g + 0 <= qrow) ? __expf(sv0 - mst) : 0.f;
      float p1 = (kv0 + 4 * g + 1 <= qrow) ? __expf(sv1 - mst) : 0.f;
      float p2 = (kv0 + 4 * g + 2 <= qrow) ? __expf(sv2 - mst) : 0.f;
      float p3 = (kv0 + 4 * g + 3 <= qrow) ? __expf(sv3 - mst) : 0.f;
      float rs = p0 + p1 + p2 + p3;
      rs += __shfl_xor(rs, 16);
      rs += __shfl_xor(rs, 32);
      lst = lst * sc + rs;

      // ---- PV: O^T += V^T * P^T; paired b128 V reads feed 2 MFMAs ---------
      f16x4 pf;
      pf[0] = (_Float16)p0; pf[1] = (_Float16)p1;
      pf[2] = (_Float16)p2; pf[3] = (_Float16)p3;
      const char* vb = kb + 16384;
      __builtin_amdgcn_s_setprio(1);
      #pragma unroll
      for (int e = 0; e < 16; ++e) {
        f16x8 vv = *(const f16x8*)(vb + e * 1024 + m * 64 + vs);
        f16x4 vlo; vlo[0] = vv[0]; vlo[1] = vv[1]; vlo[2] = vv[2]; vlo[3] = vv[3];
        f16x4 vhi; vhi[0] = vv[4]; vhi[1] = vv[5]; vhi[2] = vv[6]; vhi[3] = vv[7];
        acc[2 * e]     = __builtin_amdgcn_mfma_f32_16x16x16f16(vlo, pf, acc[2 * e],     0, 0, 0);
        acc[2 * e + 1] = __builtin_amdgcn_mfma_f32_16x16x16f16(vhi, pf, acc[2 * e + 1], 0, 0, 0);
      }
      __builtin_amdgcn_s_setprio(0);
    }
  }

  // ---- epilogue -------------------------------------------------------------
  const int q = w * 16 + m;
  if (direct) {
    float inv = 1.0f / lst;
    float* orow = Out + ((size_t)(b * SS + qrow)) * 1024 + 512;
    #pragma unroll
    for (int dt = 0; dt < 32; ++dt) {
      float4 v4;
      v4.x = acc[dt][0] * inv; v4.y = acc[dt][1] * inv;
      v4.z = acc[dt][2] * inv; v4.w = acc[dt][3] * inv;
      *(float4*)(orow + dt * 16 + g * 4) = v4;
    }
  } else {
    int uoff = 0, wsoff = 0;
    for (int tt = 0; tt < t; ++tt) {
      int rtt = rt_of(tt, CC);
      if (rtt >= 2) uoff += rtt;
      if (rtt > 4)  wsoff += rtt - 4;
    }
    if (ln < 16) {
      float* mlp = MLp + ((size_t)(b * TU + uoff + r) * 64 + q) * 2;
      mlp[0] = mst; mlp[1] = lst;
    }
    char* rowb;
    if (r < 4) {
      int hoff = (r & 2) ? ((r & 1) * 1024) : (2048 + (r & 1) * 1024);
      rowb = (char*)Out + (size_t)(b * SS + t * 64 + q) * 4096 + hoff;
    } else {
      rowb = wsOp + ((size_t)(b * WSB + wsoff + (r - 4)) * 64 + q) * 1024;
    }
    #pragma unroll
    for (int dt = 0; dt < 32; ++dt) {
      PK4 p;
      p.h[0] = (_Float16)acc[dt][0]; p.h[1] = (_Float16)acc[dt][1];
      p.h[2] = (_Float16)acc[dt][2]; p.h[3] = (_Float16)acc[dt][3];
      *(uint2*)(rowb + dt * 32 + g * 8) = p.u;
    }
  }
}

// ---------------------------------------------------------------------------
// Fused combine + orig copy. One wave per output row (4 rows / 256-thr block).
// Each wave touches ONLY its own row (+ws/ML reads): reads the hosted slot
// chunks (bytes of this row), merges, then writes right half (merged) and
// left half (orig). Wave-lockstep + may-alias dependency ordering guarantees
// loads precede the stores. Correctness proven by the round-7 bench.
// ---------------------------------------------------------------------------
__global__ __launch_bounds__(256)
void combine_kernel(const char* __restrict__ wsOp, const float* __restrict__ MLp,
                    const float* __restrict__ orig, float* Out,
                    int CC, int TU, int WSB)
{
  const int row = blockIdx.x * 4 + (threadIdx.x >> 6);
  const int ln  = threadIdx.x & 63;
  const int b = row >> 11;
  const int s = row & 2047;
  const int t = s >> 6;
  const int q = s & 63;
  const int c0 = ln * 8;                 // 8 f32 output cols per lane

  const float* op = orig + (size_t)row * 512 + c0;
  float4 og0 = *(const float4*)op;
  float4 og1 = *(const float4*)(op + 4);

  const int Rt = rt_of(t, CC);
  if (Rt >= 2) {
    int uoff = 0, wsoff = 0;
    for (int tt = 0; tt < t; ++tt) {
      int rtt = rt_of(tt, CC);
      if (rtt >= 2) uoff += rtt;
      if (rtt > 4)  wsoff += rtt - 4;
    }
    float mr[MAXR], lr[MAXR];
    #pragma unroll
    for (int rr = 0; rr < MAXR; ++rr) { mr[rr] = NEG_BIG; lr[rr] = 0.f; }
    #pragma unroll
    for (int rr = 0; rr < MAXR; ++rr) {
      if (rr < Rt) {
        const float* p = MLp + ((size_t)(b * TU + uoff + rr) * 64 + q) * 2;
        mr[rr] = p[0]; lr[rr] = p[1];
      }
    }
    float M = NEG_BIG;
    #pragma unroll
    for (int rr = 0; rr < MAXR; ++rr) M = fmaxf(M, mr[rr]);

    float L = 0.f;
    float o[8];
    #pragma unroll
    for (int e = 0; e < 8; ++e) o[e] = 0.f;

    #pragma unroll
    for (int rr = 0; rr < MAXR; ++rr) {
      if (rr < Rt) {
        float wgt = __expf(mr[rr] - M);
        L += wgt * lr[rr];
        const char* sp;
        if (rr < 4) {
          int hoff = (rr & 2) ? ((rr & 1) * 1024) : (2048 + (rr & 1) * 1024);
          sp = (const char*)Out + (size_t)row * 4096 + hoff + c0 * 2;
        } else {
          sp = wsOp + ((size_t)(b * WSB + wsoff + (rr - 4)) * 64 + q) * 1024 + c0 * 2;
        }
        f16x8 v = *(const f16x8*)sp;
        #pragma unroll
        for (int e = 0; e < 8; ++e) o[e] += wgt * (float)v[e];
      }
    }
    float inv = 1.0f / L;
    float4 r0, r1;
    r0.x = o[0] * inv; r0.y = o[1] * inv; r0.z = o[2] * inv; r0.w = o[3] * inv;
    r1.x = o[4] * inv; r1.y = o[5] * inv; r1.z = o[6] * inv; r1.w = o[7] * inv;
    *(float4*)(Out + (size_t)row * 1024 + 512 + c0)     = r0;
    *(float4*)(Out + (size_t)row * 1024 + 512 + c0 + 4) = r1;
  }
  // left half: original (overwrites hosted r=2,3 bytes AFTER the reads above)
  *(float4*)(Out + (size_t)row * 1024 + c0)     = og0;
  *(float4*)(Out + (size_t)row * 1024 + c0 + 4) = og1;
}

extern "C" void kernel_launch(void* const* d_in, const int* in_sizes, int n_in,
                              void* d_out, int out_size, void* d_ws, size_t ws_size,
                              hipStream_t stream)
{
  (void)in_sizes; (void)n_in; (void)out_size;
  const float* keys     = (const float*)d_in[0];
  const float* queries  = (const float*)d_in[1];
  const float* values   = (const float*)d_in[2];
  const float* original = (const float*)d_in[3];
  float* out = (float*)d_out;

  const size_t PREPB = (size_t)BB * 128 * 32768;   // 16,777,216

  // Ladder: CC=19 -> grid 508 <= 512 (all-resident), chain 19 = provable
  // floor under the 512-block cap. Self-hosted slots (4 free per multi
  // unit); only r>=4 need ws: need(19) = 23.84MB <= proven ws >= 30.15MB.
  const int CCcand[6] = {19, 20, 24, 32, 64, 128};
  int CC = 128, TU = 0, WSB = 0, units = NTQ;
  for (int i = 0; i < 6; ++i) {
    int cc = CCcand[i];
    int tu = 0, wsb = 0, un = 0;
    for (int t = 0; t < NTQ; ++t) {
      int rt = rt_of(t, cc);
      un += rt;
      if (rt >= 2) tu += rt;
      if (rt > 4)  wsb += rt - 4;
    }
    size_t need = PREPB + (size_t)BB * tu * 512 + (size_t)BB * wsb * 65536;
    if (ws_size >= need && BB * un <= 512) { CC = cc; TU = tu; WSB = wsb; units = un; break; }
  }

  char* PREP = (char*)d_ws;
  float* MLp = (float*)(PREP + PREPB);
  char* wsOp = PREP + PREPB + (size_t)BB * TU * 512;

  hipLaunchKernelGGL(prep_kernel, dim3(BB * 128), dim3(256), 0, stream,
                     keys, values, PREP);

  hipLaunchKernelGGL(attn_kernel, dim3(BB * units), dim3(256), 0, stream,
                     PREP, queries, wsOp, MLp, out, CC, TU, WSB);

  hipLaunchKernelGGL(combine_kernel, dim3((BB * SS) / 4), dim3(256), 0, stream,
                     wsOp, MLp, original, out, CC, TU, WSB);
}